// Round 4
// baseline (286.217 us; speedup 1.0000x reference)
//
#include <hip/hip_runtime.h>
#include <cstdint>
#include <cstddef>

#define B_    8
#define N_    2048
#define FIN   128
#define FOUT  64
#define ALPHA 0.2f
#define NEG_BIG -9.0e15f

typedef __attribute__((ext_vector_type(8))) _Float16 half8;
typedef __attribute__((ext_vector_type(4))) float float4v;

// ---------------------------------------------------------------------------
// Kernel 1: wh = x @ W  (fp32 accumulate), store whT[b][f][j] as fp16,
//           s1 = wh@a1, s2 = wh@a2 (fp32).
// ---------------------------------------------------------------------------
__global__ __launch_bounds__(256, 4) void k1_wh(
    const float* __restrict__ x, const float* __restrict__ W,
    const float* __restrict__ w2, _Float16* __restrict__ whT,
    float* __restrict__ s1, float* __restrict__ s2)
{
    int t = threadIdx.x, lane = t & 63, w = t >> 6;
    float a1 = w2[lane], a2 = w2[FOUT + lane];
    int rowBase = blockIdx.x * 32 + w * 8;   // 32 rows/block, 8 rows/wave
    for (int rr = 0; rr < 8; ++rr) {
        int row = __builtin_amdgcn_readfirstlane(rowBase + rr);  // wave-uniform
        const float* xr = x + (size_t)row * FIN;
        float acc = 0.f;
        #pragma unroll
        for (int k = 0; k < FIN; ++k)
            acc = fmaf(xr[k], W[k * FOUT + lane], acc);
        int b = row >> 11, j = row & (N_ - 1);
        whT[((size_t)b * FOUT + lane) * N_ + j] = (_Float16)acc;
        float p1 = acc * a1, p2 = acc * a2;
        #pragma unroll
        for (int m = 32; m >= 1; m >>= 1) {
            p1 += __shfl_xor(p1, m);
            p2 += __shfl_xor(p2, m);
        }
        if (lane == 0) { s1[row] = p1; s2[row] = p2; }
    }
}

// ---------------------------------------------------------------------------
// Kernel 2: masked softmax + PV via MFMA, split-j across 2 blocks/row-group.
// Block = 16 rows x 1024 j (2 chunks of 512), 4 waves, single-buffer LDS
// (17 KB -> 8 blocks/CU at VGPR=64, __launch_bounds__(256,8)).
// m^ = leaky(s1_i + max_j s2_j) is a shared upper bound on every row max,
// so softmax partials from the two j-halves merge by PLAIN ADDITION:
// acc -> atomicAdd into d_out, l -> atomicAdd into lP; k3 normalizes.
// A-frag: row=lane&15, k=quad*8+e. C/D: col=lane&15, row=quad*4+reg.
// ---------------------------------------------------------------------------
__global__ __launch_bounds__(256, 8) void k2_attn(
    const int* __restrict__ adj, const _Float16* __restrict__ whT,
    const float* __restrict__ s1, const float* __restrict__ s2,
    float* __restrict__ accP, float* __restrict__ lP)
{
    __shared__ __attribute__((aligned(16))) _Float16 pT[16][520];
    __shared__ float smaxL[4];

    int t = threadIdx.x, lane = t & 63, w = t >> 6;
    int rg = blockIdx.x >> 1;            // global row-group 0..1023
    int jh = blockIdx.x & 1;             // j-half
    int b = rg >> 7;
    int i0 = (rg & 127) << 4;
    int j0 = jh << 10;

    // --- exact S2MAX over the FULL batch row range (shared across j-halves) ---
    const float4* s2v = (const float4*)(s2 + (size_t)b * N_);
    float4 ua = s2v[t], ub = s2v[t + 256];
    float vm = fmaxf(fmaxf(fmaxf(ua.x, ua.y), fmaxf(ua.z, ua.w)),
                     fmaxf(fmaxf(ub.x, ub.y), fmaxf(ub.z, ub.w)));
    #pragma unroll
    for (int m = 32; m >= 1; m >>= 1) vm = fmaxf(vm, __shfl_xor(vm, m));
    if (lane == 0) smaxL[w] = vm;
    __syncthreads();
    float s2max = fmaxf(fmaxf(smaxL[0], smaxL[1]), fmaxf(smaxL[2], smaxL[3]));

    int l15 = lane & 15, quad = lane >> 4;
    int f0 = w * 16;

    float s1r[4], negmh[4], lacc[4];
    #pragma unroll
    for (int rr = 0; rr < 4; ++rr) {
        float sv = s1[(size_t)b * N_ + i0 + w * 4 + rr];  // wave-uniform
        float mh = sv + s2max;
        mh = fmaxf(mh, ALPHA * mh);      // leaky(s1_i + s2max) >= row max
        s1r[rr] = sv;
        negmh[rr] = -mh;
        lacc[rr] = 0.f;
    }

    float4v acc = {0, 0, 0, 0};
    const _Float16* wB = whT + ((size_t)b * FOUT + f0 + l15) * N_ + j0 + quad * 8;

    for (int jc = 0; jc < 1024; jc += 512) {
        // s2 chunk: 8 consecutive floats per lane, reused across 4 rows
        const float* s2c = s2 + (size_t)b * N_ + j0 + jc + lane * 8;
        float4 sa = *(const float4*)s2c;
        float4 sb = *(const float4*)(s2c + 4);
        float ss[8] = {sa.x, sa.y, sa.z, sa.w, sb.x, sb.y, sb.z, sb.w};

        #pragma unroll
        for (int rr = 0; rr < 4; ++rr) {
            int r = w * 4 + rr;
            const int* ap = adj + ((size_t)b * N_ + i0 + r) * N_ + j0 + jc + lane * 8;
            int4 aj0 = *(const int4*)ap;
            int4 aj1 = *(const int4*)(ap + 4);
            int aa[8] = {aj0.x, aj0.y, aj0.z, aj0.w, aj1.x, aj1.y, aj1.z, aj1.w};
            half8 pf;
            float ls = 0.f;
            #pragma unroll
            for (int e = 0; e < 8; ++e) {
                float v = s1r[rr] + ss[e];
                v = fmaxf(v, ALPHA * v);                 // leaky relu
                v = (aa[e] > 0) ? v : NEG_BIG;           // mask
                float tt = fmaxf(v + negmh[rr], -76.f);  // masked -> exp ~ 0
                float p = __expf(tt);                    // p in (0,1]
                ls += p;
                pf[e] = (_Float16)p;
            }
            lacc[rr] += ls;
            *(half8*)&pT[r][lane * 8] = pf;              // contiguous b128
        }
        __syncthreads();

        // MFMA phase: wave w's 16-feature group, K-chunk of 512
        const _Float16* wp = wB + jc;
        #pragma unroll
        for (int kk = 0; kk < 16; ++kk) {
            half8 af = *(const half8*)&pT[l15][kk * 32 + quad * 8];
            half8 bf = *(const half8*)(wp + kk * 32);
            acc = __builtin_amdgcn_mfma_f32_16x16x32_f16(af, bf, acc, 0, 0, 0);
        }
        __syncthreads();
    }

    // merge: l partials (wave-owned rows) and acc partials via fp32 atomics
    #pragma unroll
    for (int rr = 0; rr < 4; ++rr) {
        float v = lacc[rr];
        #pragma unroll
        for (int m = 32; m >= 1; m >>= 1) v += __shfl_xor(v, m);
        if (lane == 0) atomicAdd(&lP[(size_t)b * N_ + i0 + w * 4 + rr], v);
    }
    #pragma unroll
    for (int reg = 0; reg < 4; ++reg) {
        int row = quad * 4 + reg;
        atomicAdd(&accP[((size_t)b * N_ + i0 + row) * FOUT + f0 + l15], acc[reg]);
    }
}

// ---------------------------------------------------------------------------
// Kernel 3: normalize + ELU, in place on d_out (acc partials), float4-wide.
// ---------------------------------------------------------------------------
__global__ __launch_bounds__(256, 8) void k3_norm(
    float* __restrict__ accP, const float* __restrict__ lP)
{
    int idx = blockIdx.x * 256 + threadIdx.x;       // 262144 float4 groups
    int row = idx >> 4;                             // 16 float4 per row of 64
    float li = 1.0f / lP[row];
    float4 v = ((const float4*)accP)[idx];
    float r0 = v.x * li, r1 = v.y * li, r2 = v.z * li, r3 = v.w * li;
    r0 = (r0 > 0.f) ? r0 : (__expf(r0) - 1.f);
    r1 = (r1 > 0.f) ? r1 : (__expf(r1) - 1.f);
    r2 = (r2 > 0.f) ? r2 : (__expf(r2) - 1.f);
    r3 = (r3 > 0.f) ? r3 : (__expf(r3) - 1.f);
    float4 o = {r0, r1, r2, r3};
    ((float4*)accP)[idx] = o;
}

// ---------------------------------------------------------------------------
extern "C" void kernel_launch(void* const* d_in, const int* in_sizes, int n_in,
                              void* d_out, int out_size, void* d_ws, size_t ws_size,
                              hipStream_t stream) {
    const float* x   = (const float*)d_in[0];
    const int*   adj = (const int*)d_in[1];
    const float* W   = (const float*)d_in[2];
    const float* w2  = (const float*)d_in[3];
    float* out = (float*)d_out;

    _Float16* whT = (_Float16*)d_ws;                                  // 2 MiB
    float* s1 = (float*)((char*)d_ws + (size_t)B_ * FOUT * N_ * 2);   // 64 KiB
    float* s2 = s1 + (size_t)B_ * N_;                                 // 64 KiB
    float* lP = s2 + (size_t)B_ * N_;                                 // 64 KiB

    hipMemsetAsync(d_out, 0, (size_t)B_ * N_ * FOUT * sizeof(float), stream);
    hipMemsetAsync(lP, 0, (size_t)B_ * N_ * sizeof(float), stream);

    k1_wh<<<(B_ * N_) / 32, 256, 0, stream>>>(x, W, w2, whT, s1, s2);
    k2_attn<<<(B_ * N_) / 16 * 2, 256, 0, stream>>>(adj, whT, s1, s2, out, lP);
    k3_norm<<<(B_ * N_ * FOUT / 4) / 256, 256, 0, stream>>>(out, lP);
}

// Round 5
// 283.889 us; speedup vs baseline: 1.0082x; 1.0082x over previous
//
#include <hip/hip_runtime.h>
#include <cstdint>
#include <cstddef>

#define B_    8
#define N_    2048
#define FIN   128
#define FOUT  64
#define ALPHA 0.2f
#define NEG_BIG -9.0e15f

typedef __attribute__((ext_vector_type(8))) _Float16 half8;
typedef __attribute__((ext_vector_type(4))) float float4v;

// ---------------------------------------------------------------------------
// Kernel 1: wh = x @ W  (fp32 accumulate), store whT[b][f][j] as fp16,
//           s1 = wh@a1, s2 = wh@a2 (fp32).
// ---------------------------------------------------------------------------
__global__ __launch_bounds__(256, 4) void k1_wh(
    const float* __restrict__ x, const float* __restrict__ W,
    const float* __restrict__ w2, _Float16* __restrict__ whT,
    float* __restrict__ s1, float* __restrict__ s2)
{
    int t = threadIdx.x, lane = t & 63, w = t >> 6;
    float a1 = w2[lane], a2 = w2[FOUT + lane];
    int rowBase = blockIdx.x * 32 + w * 8;   // 32 rows/block, 8 rows/wave
    for (int rr = 0; rr < 8; ++rr) {
        int row = __builtin_amdgcn_readfirstlane(rowBase + rr);  // wave-uniform
        const float* xr = x + (size_t)row * FIN;
        float acc = 0.f;
        #pragma unroll
        for (int k = 0; k < FIN; ++k)
            acc = fmaf(xr[k], W[k * FOUT + lane], acc);
        int b = row >> 11, j = row & (N_ - 1);
        whT[((size_t)b * FOUT + lane) * N_ + j] = (_Float16)acc;
        float p1 = acc * a1, p2 = acc * a2;
        #pragma unroll
        for (int m = 32; m >= 1; m >>= 1) {
            p1 += __shfl_xor(p1, m);
            p2 += __shfl_xor(p2, m);
        }
        if (lane == 0) { s1[row] = p1; s2[row] = p2; }
    }
}

// ---------------------------------------------------------------------------
// Kernel 2: masked softmax + PV via MFMA. Block = 16 rows x full j, 4 waves.
// MLP-first restructure (R4 lesson: VGPR squeeze killed per-wave memory
// parallelism; occupancy is NOT the lever):
//  * __launch_bounds__(256,3) -> ~170 VGPR budget, no spills, deep batching.
//  * Per 512-chunk: issue 8 B-frag loads (first half) + all 8 adj int4 + s2
//    BEFORE any compute -> one latency exposure per phase, not 16.
//  * Second-half B-frags load during first-half MFMAs (global, barrier-free).
//  * XCD swizzle: b = blockIdx&7 -> batch-b blocks share one XCD whose L2
//    holds whT[b] (256 KB) + s1/s2 -> B-frags are ~200cyc L2 hits, not LLC.
// m^ = leaky(s1_i + max_j s2_j) >= row max -> partials need no rescaling;
// masked entries floor at exp(-76)~0 (reproduces uniform softmax for
// all-masked rows). A-frag: row=lane&15, k=quad*8+e. C/D: col=lane&15,
// row=quad*4+reg. pT stride 520 halfs -> A-reads 8 lanes per 4-bank group
// (structural minimum).
// ---------------------------------------------------------------------------
__global__ __launch_bounds__(256, 3) void k2_attn(
    const int* __restrict__ adj, const _Float16* __restrict__ whT,
    const float* __restrict__ s1, const float* __restrict__ s2,
    float* __restrict__ out)
{
    __shared__ __attribute__((aligned(16))) _Float16 pT[16][520];
    __shared__ float lL[16];
    __shared__ float smaxL[4];

    int t = threadIdx.x, lane = t & 63, w = t >> 6;
    int b = blockIdx.x & 7;               // XCD-aware: batch -> XCD
    int i0 = (blockIdx.x >> 3) << 4;      // 128 row-groups per batch

    // --- exact S2MAX over batch b (8 KB, L2-hot on this XCD) ---
    const float4* s2v = (const float4*)(s2 + (size_t)b * N_);
    float4 ua = s2v[t], ub = s2v[t + 256];
    float vm = fmaxf(fmaxf(fmaxf(ua.x, ua.y), fmaxf(ua.z, ua.w)),
                     fmaxf(fmaxf(ub.x, ub.y), fmaxf(ub.z, ub.w)));
    #pragma unroll
    for (int m = 32; m >= 1; m >>= 1) vm = fmaxf(vm, __shfl_xor(vm, m));
    if (lane == 0) smaxL[w] = vm;
    __syncthreads();
    float s2max = fmaxf(fmaxf(smaxL[0], smaxL[1]), fmaxf(smaxL[2], smaxL[3]));

    int l15 = lane & 15, quad = lane >> 4;
    int f0 = w * 16;

    float s1r[4], negmh[4], lacc[4];
    #pragma unroll
    for (int rr = 0; rr < 4; ++rr) {
        float sv = s1[(size_t)b * N_ + i0 + w * 4 + rr];  // wave-uniform
        float mh = sv + s2max;
        mh = fmaxf(mh, ALPHA * mh);      // leaky(s1_i + s2max) >= row max
        s1r[rr] = sv;
        negmh[rr] = -mh;
        lacc[rr] = 0.f;
    }

    const int*      adjB = adj + ((size_t)b * N_ + i0 + w * 4) * N_ + lane * 8;
    const float*    s2B  = s2 + (size_t)b * N_ + lane * 8;
    const _Float16* wB   = whT + ((size_t)b * FOUT + f0 + l15) * N_ + quad * 8;

    float4v acc = {0, 0, 0, 0};

    #pragma unroll
    for (int c = 0; c < 4; ++c) {
        const int jc = c * 512;
        const _Float16* wp = wB + jc;

        // ---- issue ALL loads for this phase up front (max MLP) ----
        half8 bfr0[8];
        #pragma unroll
        for (int kk = 0; kk < 8; ++kk)
            bfr0[kk] = *(const half8*)(wp + kk * 32);     // B first half (L2)

        int4 aj[4][2];
        #pragma unroll
        for (int rr = 0; rr < 4; ++rr) {
            const int* ap = adjB + (size_t)rr * N_ + jc;  // HBM, coalesced
            aj[rr][0] = *(const int4*)ap;
            aj[rr][1] = *(const int4*)(ap + 4);
        }
        const float* s2c = s2B + jc;
        float4 sa = *(const float4*)s2c;
        float4 sb = *(const float4*)(s2c + 4);
        float ss[8] = {sa.x, sa.y, sa.z, sa.w, sb.x, sb.y, sb.z, sb.w};

        // ---- p-phase: 4 rows x 8 elems per lane ----
        #pragma unroll
        for (int rr = 0; rr < 4; ++rr) {
            int aa[8] = {aj[rr][0].x, aj[rr][0].y, aj[rr][0].z, aj[rr][0].w,
                         aj[rr][1].x, aj[rr][1].y, aj[rr][1].z, aj[rr][1].w};
            half8 pf;
            float ls = 0.f;
            #pragma unroll
            for (int e = 0; e < 8; ++e) {
                float v = s1r[rr] + ss[e];
                v = fmaxf(v, ALPHA * v);                 // leaky relu
                v = (aa[e] > 0) ? v : NEG_BIG;           // mask
                float tt = fmaxf(v + negmh[rr], -76.f);  // masked -> exp ~ 0
                float p = __expf(tt);                    // p in (0,1]
                ls += p;
                pf[e] = (_Float16)p;
            }
            lacc[rr] += ls;
            *(half8*)&pT[w * 4 + rr][lane * 8] = pf;     // contiguous b128
        }

        if (c == 3) {
            // final row-sum reduction before the barrier that publishes pT
            #pragma unroll
            for (int rr = 0; rr < 4; ++rr) {
                float v = lacc[rr];
                #pragma unroll
                for (int m = 32; m >= 1; m >>= 1) v += __shfl_xor(v, m);
                if (lane == 0) lL[w * 4 + rr] = v;
            }
        }
        __syncthreads();

        // ---- MFMA phase: second-half B loads overlap first-half MFMAs ----
        half8 bfr1[8];
        #pragma unroll
        for (int kk = 0; kk < 8; ++kk)
            bfr1[kk] = *(const half8*)(wp + (kk + 8) * 32);

        #pragma unroll
        for (int kk = 0; kk < 8; ++kk) {
            half8 af = *(const half8*)&pT[l15][kk * 32 + quad * 8];
            acc = __builtin_amdgcn_mfma_f32_16x16x32_f16(af, bfr0[kk], acc, 0, 0, 0);
        }
        #pragma unroll
        for (int kk = 0; kk < 8; ++kk) {
            half8 af = *(const half8*)&pT[l15][(kk + 8) * 32 + quad * 8];
            acc = __builtin_amdgcn_mfma_f32_16x16x32_f16(af, bfr1[kk], acc, 0, 0, 0);
        }
        __syncthreads();
    }

    // epilogue: normalize, ELU, store. D: row=quad*4+reg, col=f0+l15
    #pragma unroll
    for (int reg = 0; reg < 4; ++reg) {
        int row = quad * 4 + reg;
        float val = acc[reg] / lL[row];
        val = (val > 0.f) ? val : (__expf(val) - 1.f);   // ELU
        out[((size_t)b * N_ + i0 + row) * FOUT + f0 + l15] = val;
    }
}

// ---------------------------------------------------------------------------
extern "C" void kernel_launch(void* const* d_in, const int* in_sizes, int n_in,
                              void* d_out, int out_size, void* d_ws, size_t ws_size,
                              hipStream_t stream) {
    const float* x   = (const float*)d_in[0];
    const int*   adj = (const int*)d_in[1];
    const float* W   = (const float*)d_in[2];
    const float* w2  = (const float*)d_in[3];
    float* out = (float*)d_out;

    _Float16* whT = (_Float16*)d_ws;                                  // 2 MiB
    float* s1 = (float*)((char*)d_ws + (size_t)B_ * FOUT * N_ * 2);   // 64 KiB
    float* s2 = s1 + (size_t)B_ * N_;                                 // 64 KiB

    k1_wh<<<(B_ * N_) / 32, 256, 0, stream>>>(x, W, w2, whT, s1, s2);
    k2_attn<<<(B_ * N_) / 16, 256, 0, stream>>>(adj, whT, s1, s2, out);
}